// Round 8
// baseline (201.507 us; speedup 1.0000x reference)
//
#include <hip/hip_runtime.h>
#include <hip/hip_bf16.h>

// B=4, S=2048, D=1024, H=16, HD=64
constexpr int Sc = 2048, Dc = 1024;

typedef __attribute__((ext_vector_type(8))) short bf16x8;
typedef __attribute__((ext_vector_type(4))) short short4v;
typedef __attribute__((ext_vector_type(4))) float f32x4;
typedef __attribute__((ext_vector_type(16))) float f32x16;

static __device__ __forceinline__ short f2bf(float f) {
  __hip_bfloat16 h = __float2bfloat16(f);
  short s; __builtin_memcpy(&s, &h, 2);
  return s;
}

// packed f32x2 -> bf16x2 (RNE), single instruction on gfx950 (HW-verified r6)
static __device__ __forceinline__ unsigned int cvtpk(float lo, float hi) {
  unsigned int r;
  asm("v_cvt_pk_bf16_f32 %0, %1, %2" : "=v"(r) : "v"(lo), "v"(hi));
  return r;
}

typedef __attribute__((address_space(3))) short lds_short_t;

// async global->LDS, 16B per lane; LDS dest = wave-uniform base + lane*16
static __device__ __forceinline__ void gload16(const short* g, lds_short_t* l) {
  __builtin_amdgcn_global_load_lds(
      (const __attribute__((address_space(1))) unsigned int*)g,
      (__attribute__((address_space(3))) unsigned int*)l, 16, 0, 0);
}

__global__ __launch_bounds__(256) void cvt_f32_bf16(const float* __restrict__ src,
                                                    short* __restrict__ dst,
                                                    int n4) {
  int i = blockIdx.x * 256 + threadIdx.x;
  if (i >= n4) return;
  float4 v = ((const float4*)src)[i];
  short4v o;
  o.x = f2bf(v.x); o.y = f2bf(v.y); o.z = f2bf(v.z); o.w = f2bf(v.w);
  ((short4v*)dst)[i] = o;
}

// all 4 weight matrices in one launch: gridDim=(1024,4)
__global__ __launch_bounds__(256) void cvt_w4(const float* __restrict__ w0,
                                              const float* __restrict__ w1,
                                              const float* __restrict__ w2,
                                              const float* __restrict__ w3,
                                              short* __restrict__ dst) {
  const int y = blockIdx.y;
  const float* src = (y == 0) ? w0 : (y == 1) ? w1 : (y == 2) ? w2 : w3;
  int i = blockIdx.x * 256 + threadIdx.x;  // < 262144 exactly
  float4 v = ((const float4*)src)[i];
  short4v o;
  o.x = f2bf(v.x); o.y = f2bf(v.y); o.z = f2bf(v.z); o.w = f2bf(v.w);
  ((short4v*)(dst))[(size_t)y * 262144 + i] = o;
}

// ---------------------------------------------------------------------------
// QKV GEMM, 8-phase 256x256 template (T2 swizzle + T3/T4 counted vmcnt + T5).
// A bf16 [8192][1024]; W bf16 [3072][1024] (Wq|Wk|Wv rows); C = A @ W^T.
// 512 thr = 8 waves (2M x 4N), per-wave 128x64 out, BK=64, 16 K-tiles.
// LDS 2 dbuf x 4 regions x 16KB:
//   R0 = A rows {0-63,128-191}   (mh0; read at p0)
//   R1 = B rows {wn*64+0..31}    (nh0; read at p0 and p3)
//   R2 = B rows {wn*64+32..63}   (nh1; read at p1, frags held to p2)
//   R3 = A rows {64-127,192-255} (mh1; read at p2)
// Phase p: [ds_read; stage 1 region of kt+1 -> buf^1; vmcnt(4); barrier;
//           setprio(1); 16 MFMA (quadrant); setprio(0); barrier]
// vmcnt(4) = 2 regions (x2 loads/wave) in flight; each region has >=3 phases
// of flight before use; the wait precedes a barrier so ALL waves' DMA for a
// region is complete before any wave reads it (per-wave vmcnt + barrier).
// Swizzle: LDS linear; source granule pre-XOR (g^ridx&7); read granule
// XOR'd the same way (rule #21) -> 2 lanes/bank-slot, conflict-free.
// ---------------------------------------------------------------------------
__global__ __launch_bounds__(512, 2) void gemm_qkv_8p(
    const short* __restrict__ A, const short* __restrict__ W,
    short* __restrict__ Qb, short* __restrict__ Kb, short* __restrict__ Vt) {
  __shared__ short lds[2][4][8192];  // 128 KiB
  const int tid = threadIdx.x, lane = tid & 63, w = tid >> 6;
  const int wm = w >> 2, wn = w & 3;
  const int ll = lane & 15, lh = lane >> 4;
  // XCD-bijective swizzle (nwg=384=8*48)
  const int wg = ((int)blockIdx.x & 7) * 48 + ((int)blockIdx.x >> 3);
  const int m0 = (wg / 12) * 256, n0 = (wg % 12) * 256;

  lds_short_t* L3 = (lds_short_t*)&lds[0][0][0];

  // staging geometry: region = 16KB = 1024 slots of 16B; 2 issues/thread.
  const short* Asrc[2];
  const short* Bsrc[2];
  int dstOff[2];
#pragma unroll
  for (int i = 0; i < 2; ++i) {
    int slot = i * 512 + tid;
    int ridx = slot >> 3, g = slot & 7;
    int gp = g ^ (ridx & 7);  // pre-swizzled source granule
    Asrc[i] = A + (size_t)(m0 + (ridx & 63) + ((ridx >> 6) << 7)) * 1024 + gp * 8;
    Bsrc[i] = W + (size_t)(n0 + ((ridx >> 5) << 6) + (ridx & 31)) * 1024 + gp * 8;
    dstOff[i] = (i * 512 + w * 64) * 8;  // wave-uniform LDS base (shorts)
  }

  f32x4 acc[8][4] = {};
  bf16x8 fa[4][2];   // current A-mh frags
  bf16x8 fb0[2][2];  // B-nh0 frags (reloaded at p3)
  bf16x8 fb1[2][2];  // B-nh1 frags (held p1->p2)

  // prologue: stage tile 0 regions R0,R1,R2,R3 into buf 0 (issue order = age)
#pragma unroll
  for (int i = 0; i < 2; ++i) gload16(Asrc[i], L3 + 0 * 8192 + dstOff[i]);
#pragma unroll
  for (int i = 0; i < 2; ++i) gload16(Bsrc[i], L3 + 1 * 8192 + dstOff[i]);
#pragma unroll
  for (int i = 0; i < 2; ++i)
    gload16(Bsrc[i] + 32 * 1024, L3 + 2 * 8192 + dstOff[i]);
#pragma unroll
  for (int i = 0; i < 2; ++i)
    gload16(Asrc[i] + 64 * 1024, L3 + 3 * 8192 + dstOff[i]);
  asm volatile("s_waitcnt vmcnt(4)" ::: "memory");  // R0,R1 landed (per-wave)
  __builtin_amdgcn_s_barrier();                     // -> landed for all waves

  for (int kt = 0; kt < 16; ++kt) {
    const int c = kt & 1;
    const int cb = c * 32768, nb = (c ^ 1) * 32768;
    const int kn = (kt + 1) * 64;

    // ---------------- phase 0: quadrant (mh0, nh0) ----------------
#pragma unroll
    for (int mi = 0; mi < 4; ++mi) {
      int ridx = wm * 64 + mi * 16 + ll;
#pragma unroll
      for (int kh = 0; kh < 2; ++kh)
        fa[mi][kh] = *(const bf16x8*)&lds[c][0][ridx * 64 +
                                               (((kh * 4 + lh) ^ (ll & 7)) * 8)];
    }
#pragma unroll
    for (int ni = 0; ni < 2; ++ni) {
      int ridx = wn * 32 + ni * 16 + ll;
#pragma unroll
      for (int kh = 0; kh < 2; ++kh)
        fb0[ni][kh] = *(const bf16x8*)&lds[c][1][ridx * 64 +
                                                 (((kh * 4 + lh) ^ (ll & 7)) * 8)];
    }
    if (kt < 15) {  // stage R0' (A-mh0 of kt+1)
#pragma unroll
      for (int i = 0; i < 2; ++i)
        gload16(Asrc[i] + kn, L3 + nb + 0 * 8192 + dstOff[i]);
    }
    asm volatile("s_waitcnt vmcnt(4)" ::: "memory");
    __builtin_amdgcn_s_barrier();
    __builtin_amdgcn_s_setprio(1);
#pragma unroll
    for (int mi = 0; mi < 4; ++mi)
#pragma unroll
      for (int ni = 0; ni < 2; ++ni)
#pragma unroll
        for (int kh = 0; kh < 2; ++kh)
          acc[mi][ni] = __builtin_amdgcn_mfma_f32_16x16x32_bf16(
              fa[mi][kh], fb0[ni][kh], acc[mi][ni], 0, 0, 0);
    __builtin_amdgcn_s_setprio(0);
    __builtin_amdgcn_s_barrier();

    // ---------------- phase 1: quadrant (mh0, nh1) ----------------
#pragma unroll
    for (int ni = 0; ni < 2; ++ni) {
      int ridx = wn * 32 + ni * 16 + ll;
#pragma unroll
      for (int kh = 0; kh < 2; ++kh)
        fb1[ni][kh] = *(const bf16x8*)&lds[c][2][ridx * 64 +
                                                 (((kh * 4 + lh) ^ (ll & 7)) * 8)];
    }
    if (kt < 15) {  // stage R1' (B-nh0)
#pragma unroll
      for (int i = 0; i < 2; ++i)
        gload16(Bsrc[i] + kn, L3 + nb + 1 * 8192 + dstOff[i]);
    }
    asm volatile("s_waitcnt vmcnt(4)" ::: "memory");
    __builtin_amdgcn_s_barrier();
    __builtin_amdgcn_s_setprio(1);
#pragma unroll
    for (int mi = 0; mi < 4; ++mi)
#pragma unroll
      for (int ni = 0; ni < 2; ++ni)
#pragma unroll
        for (int kh = 0; kh < 2; ++kh)
          acc[mi][2 + ni] = __builtin_amdgcn_mfma_f32_16x16x32_bf16(
              fa[mi][kh], fb1[ni][kh], acc[mi][2 + ni], 0, 0, 0);
    __builtin_amdgcn_s_setprio(0);
    __builtin_amdgcn_s_barrier();

    // ---------------- phase 2: quadrant (mh1, nh1) ----------------
#pragma unroll
    for (int mi = 0; mi < 4; ++mi) {
      int ridx = wm * 64 + mi * 16 + ll;
#pragma unroll
      for (int kh = 0; kh < 2; ++kh)
        fa[mi][kh] = *(const bf16x8*)&lds[c][3][ridx * 64 +
                                               (((kh * 4 + lh) ^ (ll & 7)) * 8)];
    }
    if (kt < 15) {  // stage R2' (B-nh1)
#pragma unroll
      for (int i = 0; i < 2; ++i)
        gload16(Bsrc[i] + 32 * 1024 + kn, L3 + nb + 2 * 8192 + dstOff[i]);
    }
    asm volatile("s_waitcnt vmcnt(4)" ::: "memory");
    __builtin_amdgcn_s_barrier();
    __builtin_amdgcn_s_setprio(1);
#pragma unroll
    for (int mi = 0; mi < 4; ++mi)
#pragma unroll
      for (int ni = 0; ni < 2; ++ni)
#pragma unroll
        for (int kh = 0; kh < 2; ++kh)
          acc[4 + mi][2 + ni] = __builtin_amdgcn_mfma_f32_16x16x32_bf16(
              fa[mi][kh], fb1[ni][kh], acc[4 + mi][2 + ni], 0, 0, 0);
    __builtin_amdgcn_s_setprio(0);
    __builtin_amdgcn_s_barrier();

    // ---------------- phase 3: quadrant (mh1, nh0) ----------------
#pragma unroll
    for (int ni = 0; ni < 2; ++ni) {
      int ridx = wn * 32 + ni * 16 + ll;
#pragma unroll
      for (int kh = 0; kh < 2; ++kh)
        fb0[ni][kh] = *(const bf16x8*)&lds[c][1][ridx * 64 +
                                                 (((kh * 4 + lh) ^ (ll & 7)) * 8)];
    }
    if (kt < 15) {  // stage R3' (A-mh1)
#pragma unroll
      for (int i = 0; i < 2; ++i)
        gload16(Asrc[i] + 64 * 1024 + kn, L3 + nb + 3 * 8192 + dstOff[i]);
    }
    asm volatile("s_waitcnt vmcnt(4)" ::: "memory");
    __builtin_amdgcn_s_barrier();
    __builtin_amdgcn_s_setprio(1);
#pragma unroll
    for (int mi = 0; mi < 4; ++mi)
#pragma unroll
      for (int ni = 0; ni < 2; ++ni)
#pragma unroll
        for (int kh = 0; kh < 2; ++kh)
          acc[4 + mi][ni] = __builtin_amdgcn_mfma_f32_16x16x32_bf16(
              fa[mi][kh], fb0[ni][kh], acc[4 + mi][ni], 0, 0, 0);
    __builtin_amdgcn_s_setprio(0);
    __builtin_amdgcn_s_barrier();
  }

  // epilogue: C layout col=ll, row=lh*4+r per frag; scatter to Qb/Kb/Vt
#pragma unroll
  for (int mi = 0; mi < 8; ++mi) {
#pragma unroll
    for (int ni = 0; ni < 4; ++ni) {
#pragma unroll
      for (int r = 0; r < 4; ++r) {
        int row = m0 + wm * 128 + mi * 16 + lh * 4 + r;
        int n = n0 + wn * 64 + ni * 16 + ll;
        float v = acc[mi][ni][r];
        if (n < 1024) {
          Qb[(size_t)row * 1024 + n] = f2bf(v * 0.18033688f);  // scale*log2e
        } else if (n < 2048) {
          Kb[(size_t)row * 1024 + (n - 1024)] = f2bf(v);
        } else {
          int cc = n - 2048, hh = cc >> 6, dd = cc & 63;
          int bb = row >> 11, ss = row & 2047;
          Vt[(size_t)((bb * 16 + hh) * 64 + dd) * 2048 + ss] = f2bf(v);
        }
      }
    }
  }
}

// Out-projection GEMM (old proven 128x128 structure). A bf16 [M,1024] row-major,
// W bf16 [N,1024] row-major, f32 out + bias.
__global__ __launch_bounds__(256) void gemm_out(
    const short* __restrict__ A, const short* __restrict__ W,
    const float* __restrict__ bias, float* __restrict__ outF) {
  __shared__ short As[128 * 32];
  __shared__ short Bs[128 * 32];
  const int tid = threadIdx.x;
  const int m0 = blockIdx.x * 128, n0 = blockIdx.y * 128;
  const int lane = tid & 63, w = tid >> 6;
  const int wr = w >> 1, wc = w & 1;
  const int ll = lane & 15, lh = lane >> 4;

  lds_short_t* As3 = (lds_short_t*)As;
  lds_short_t* Bs3 = (lds_short_t*)Bs;

  const short* Abase[2];
  const short* Wbase[2];
#pragma unroll
  for (int i = 0; i < 2; ++i) {
    int slot = i * 256 + w * 64 + lane;
    int row = slot >> 2;
    int col = ((slot & 3) ^ (row & 3)) * 8;
    Abase[i] = A + (size_t)(m0 + row) * 1024 + col;
    Wbase[i] = W + (size_t)(n0 + row) * 1024 + col;
  }

  f32x4 acc[4][4] = {};

  for (int k0 = 0; k0 < 1024; k0 += 32) {
    __syncthreads();
#pragma unroll
    for (int i = 0; i < 2; ++i) {
      gload16(Abase[i] + k0, As3 + (i * 256 + w * 64) * 8);
      gload16(Wbase[i] + k0, Bs3 + (i * 256 + w * 64) * 8);
    }
    __syncthreads();

    bf16x8 fa[4], fb[4];
#pragma unroll
    for (int mi = 0; mi < 4; ++mi) {
      int r = wr * 64 + mi * 16 + ll;
      fa[mi] = *(const bf16x8*)&As[r * 32 + ((lh ^ (ll & 3)) * 8)];
    }
#pragma unroll
    for (int ni = 0; ni < 4; ++ni) {
      int r = wc * 64 + ni * 16 + ll;
      fb[ni] = *(const bf16x8*)&Bs[r * 32 + ((lh ^ (ll & 3)) * 8)];
    }
#pragma unroll
    for (int mi = 0; mi < 4; ++mi)
#pragma unroll
      for (int ni = 0; ni < 4; ++ni)
        acc[mi][ni] = __builtin_amdgcn_mfma_f32_16x16x32_bf16(
            fa[mi], fb[ni], acc[mi][ni], 0, 0, 0);
  }

#pragma unroll
  for (int mi = 0; mi < 4; ++mi)
#pragma unroll
    for (int ni = 0; ni < 4; ++ni)
#pragma unroll
      for (int r = 0; r < 4; ++r) {
        int row = m0 + wr * 64 + mi * 16 + lh * 4 + r;
        int n = n0 + wc * 64 + ni * 16 + ll;
        outF[(size_t)row * 1024 + n] = acc[mi][ni][r] + bias[n];
      }
}

// Causal flash attention, fixed-max softmax, 32x32 MFMA, swapped QK^T
// (v7: proven @ round 7).
__global__ __launch_bounds__(256, 3) void attn_v7(const short* __restrict__ Q,
                                                  const short* __restrict__ K,
                                                  const short* __restrict__ Vt,
                                                  short* __restrict__ AO) {
  __shared__ short Ks[2][64 * 64];
  __shared__ short Vs[2][64 * 64];
  const int tid = threadIdx.x, lane = tid & 63, w = tid >> 6;
  const int l31 = lane & 31, lh2 = lane >> 5;
  const int id = blockIdx.x;
  const int bh = id & 63;
  const int qs = id >> 6;
  const int jj = qs >> 2;
  const int qb = (jj == 0) ? qs : (jj == 1) ? 19 - qs : (jj == 2) ? qs - 4 : 23 - qs;
  const int b = bh >> 4, h = bh & 15;
  const int q0 = qb * 128;
  const int R = q0 + w * 32;             // wave's first q-row
  const int kw_last = (R + 31) >> 6;     // wave's diagonal k-tile
  const int kb_max = (q0 + 127) >> 6;    // block's last k-tile
  const short* Qp = Q + (size_t)b * Sc * Dc + h * 64;
  const short* Kp = K + (size_t)b * Sc * Dc + h * 64;
  const short* Vp = Vt + (size_t)bh * 64 * Sc;

  lds_short_t* Ks3 = (lds_short_t*)Ks;
  lds_short_t* Vs3 = (lds_short_t*)Vs;

  bf16x8 qf[4];
#pragma unroll
  for (int dk = 0; dk < 4; ++dk)
    qf[dk] = *(const bf16x8*)&Qp[(size_t)(R + l31) * Dc + dk * 16 + lh2 * 8];

  const short* Kst[2];
  const short* Vst[2];
  int ldsOff[2];
#pragma unroll
  for (int i = 0; i < 2; ++i) {
    int slot = i * 256 + w * 64 + lane;
    int row = slot >> 3;
    int col = ((slot & 7) ^ (row & 7)) * 8;  // pre-swizzled source group
    Kst[i] = Kp + (size_t)row * 1024 + col;
    Vst[i] = Vp + (size_t)row * 2048 + col;
    ldsOff[i] = (i * 256 + w * 64) * 8;
  }

  f32x16 o0 = {}, o1 = {};
  float lrun = 0.f;

#pragma unroll
  for (int i = 0; i < 2; ++i) {
    gload16(Kst[i], Ks3 + ldsOff[i]);
    gload16(Vst[i], Vs3 + ldsOff[i]);
  }
  int cur = 0;

  for (int kb = 0; kb <= kb_max; ++kb) {
    __syncthreads();
    if (kb < kb_max) {
      int nb = cur ^ 1;
#pragma unroll
      for (int i = 0; i < 2; ++i) {
        gload16(Kst[i] + (size_t)(kb + 1) * 65536, Ks3 + nb * 4096 + ldsOff[i]);
        gload16(Vst[i] + (kb + 1) * 64, Vs3 + nb * 4096 + ldsOff[i]);
      }
    }

    if (kb <= kw_last) {
      const bool diag = (kb == kw_last);
      const bool skipHi = diag && ((R & 63) == 0);

      f32x16 sv0 = {}, sv1 = {};
      {
        const int row = l31, rx = row & 7;
#pragma unroll
        for (int dk = 0; dk < 4; ++dk) {
          bf16x8 kf =
              *(const bf16x8*)&Ks[cur][row * 64 + (((dk * 2 + lh2) ^ rx) * 8)];
          sv0 = __builtin_amdgcn_mfma_f32_32x32x16_bf16(kf, qf[dk], sv0, 0, 0, 0);
        }
      }
      if (!skipHi) {
        const int row = 32 + l31, rx = row & 7;
#pragma unroll
        for (int dk = 0; dk < 4; ++dk) {
          bf16x8 kf =
              *(const bf16x8*)&Ks[cur][row * 64 + (((dk * 2 + lh2) ^ rx) * 8)];
          sv1 = __builtin_amdgcn_mfma_f32_32x32x16_bf16(kf, qf[dk], sv1, 0, 0, 0);
        }
      }

      float ts = 0.f;
      if (!diag) {
#pragma unroll
        for (int r = 0; r < 16; ++r) {
          float e0 = exp2f(sv0[r]);
          float e1 = exp2f(sv1[r]);
          sv0[r] = e0; sv1[r] = e1;
          ts += e0 + e1;
        }
      } else if (skipHi) {
#pragma unroll
        for (int r = 0; r < 16; ++r) {
          int kl = (r & 3) + 8 * (r >> 2) + 4 * lh2;
          float e = (kl > l31) ? 0.f : exp2f(sv0[r]);
          sv0[r] = e;
          ts += e;
        }
      } else {
#pragma unroll
        for (int r = 0; r < 16; ++r) {
          float e = exp2f(sv0[r]);
          sv0[r] = e;
          ts += e;
        }
#pragma unroll
        for (int r = 0; r < 16; ++r) {
          int kl = (r & 3) + 8 * (r >> 2) + 4 * lh2;
          float e = (kl > l31) ? 0.f : exp2f(sv1[r]);
          sv1[r] = e;
          ts += e;
        }
      }
      lrun += ts;

      short4v pa[8];
#pragma unroll
      for (int t = 0; t < 4; ++t) {
        union { unsigned int u[2]; short4v s; } pk;
        pk.u[0] = cvtpk(sv0[4 * t + 0], sv0[4 * t + 1]);
        pk.u[1] = cvtpk(sv0[4 * t + 2], sv0[4 * t + 3]);
        pa[t] = pk.s;
      }
      if (skipHi) {
        const int r0 = l31, rx0 = r0 & 7;
        const int r1 = 32 + l31, rx1 = r1 & 7;
#pragma unroll
        for (int t = 0; t < 4; ++t) {
          short4v vb0 =
              *(const short4v*)&Vs[cur][r0 * 64 + ((t ^ rx0) * 8) + lh2 * 4];
          o0 = __builtin_amdgcn_mfma_f32_32x32x8bf16_1k(pa[t], vb0, o0, 0, 0, 0);
          short4v vb1 =
              *(const short4v*)&Vs[cur][r1 * 64 + ((t ^ rx1) * 8) + lh2 * 4];
          o1 = __builtin_amdgcn_mfma_f32_32x32x8bf16_1k(pa[t], vb1, o1, 0, 0, 0);
        }
      } else {
#pragma unroll
        for (int t = 0; t < 4; ++t) {
          union { unsigned int u[2]; short4v s; } pk;
          pk.u[0] = cvtpk(sv1[4 * t + 0], sv1[4 * t + 1]);
          pk.u[1] = cvtpk(sv1[4 * t + 2], sv1[4 * t + 3]);
          pa[4 + t] = pk.s;
        }
        const int r0 = l31, rx0 = r0 & 7;
        const int r1 = 32 + l31, rx1 = r1 & 7;
#pragma unroll
        for (int t = 0; t < 8; ++t) {
          short4v vb0 =
              *(const short4v*)&Vs[cur][r0 * 64 + ((t ^ rx0) * 8) + lh2 * 4];
          o0 = __builtin_amdgcn_mfma_f32_32x32x8bf16_1k(pa[t], vb0, o0, 0, 0, 0);
        }
#pragma unroll
        for (int t = 0; t < 8; ++t) {
          short4v vb1 =
              *(const short4v*)&Vs[cur][r1 * 64 + ((t ^ rx1) * 8) + lh2 * 4];
          o1 = __builtin_amdgcn_mfma_f32_32x32x8bf16_1k(pa[t], vb1, o1, 0, 0, 0);
        }
      }
    }
    cur ^= 1;
  }

  float ltot = lrun + __shfl_xor(lrun, 32);
#pragma unroll
  for (int r = 0; r < 16; ++r) {
    int qr = (r & 3) + 8 * (r >> 2) + 4 * lh2;
    float lq = __shfl(ltot, qr);
    float inv = 1.0f / lq;
    int rowg = R + qr;
    AO[((size_t)(b * Sc + rowg)) * Dc + h * 64 + l31] = f2bf(o0[r] * inv);
    AO[((size_t)(b * Sc + rowg)) * Dc + h * 64 + 32 + l31] = f2bf(o1[r] * inv);
  }
}

extern "C" void kernel_launch(void* const* d_in, const int* in_sizes, int n_in,
                              void* d_out, int out_size, void* d_ws,
                              size_t ws_size, hipStream_t stream) {
  const float* x = (const float*)d_in[0];
  const float* Wq = (const float*)d_in[1];
  const float* Wk = (const float*)d_in[2];
  const float* Wv = (const float*)d_in[3];
  const float* Wo = (const float*)d_in[4];
  const float* bo = (const float*)d_in[5];
  float* out = (float*)d_out;

  short* Qb = (short*)d_out;
  short* Kb = Qb + (size_t)8192 * 1024;
  short* xb = (short*)d_ws;
  short* AOb = xb;  // xb dead after QKV GEMM; attention writes AOb
  short* Wc = xb + (size_t)8192 * 1024;
  short* Vt = Wc + (size_t)4096 * 1024;

  dim3 blk(256);
  hipLaunchKernelGGL(cvt_f32_bf16, dim3(8192), blk, 0, stream, x, xb, 2097152);
  hipLaunchKernelGGL(cvt_w4, dim3(1024, 4), blk, 0, stream, Wq, Wk, Wv, Wo, Wc);

  hipLaunchKernelGGL(gemm_qkv_8p, dim3(384), dim3(512), 0, stream, xb, Wc, Qb,
                     Kb, Vt);

  hipLaunchKernelGGL(attn_v7, dim3(1024), blk, 0, stream, Qb, Kb, Vt, AOb);

  hipLaunchKernelGGL(gemm_out, dim3(64, 8), blk, 0, stream, AOb,
                     Wc + (size_t)3072 * 1024, bo, out);
}

// Round 9
// 198.949 us; speedup vs baseline: 1.0129x; 1.0129x over previous
//
#include <hip/hip_runtime.h>
#include <hip/hip_bf16.h>

// B=4, S=2048, D=1024, H=16, HD=64
constexpr int Sc = 2048, Dc = 1024;

typedef __attribute__((ext_vector_type(8))) short bf16x8;
typedef __attribute__((ext_vector_type(4))) short short4v;
typedef __attribute__((ext_vector_type(4))) float f32x4;
typedef __attribute__((ext_vector_type(16))) float f32x16;

static __device__ __forceinline__ short f2bf(float f) {
  __hip_bfloat16 h = __float2bfloat16(f);
  short s; __builtin_memcpy(&s, &h, 2);
  return s;
}

// packed f32x2 -> bf16x2 (RNE), single instruction on gfx950 (HW-verified r6)
static __device__ __forceinline__ unsigned int cvtpk(float lo, float hi) {
  unsigned int r;
  asm("v_cvt_pk_bf16_f32 %0, %1, %2" : "=v"(r) : "v"(lo), "v"(hi));
  return r;
}

typedef __attribute__((address_space(3))) short lds_short_t;

// async global->LDS, 16B per lane; LDS dest = wave-uniform base + lane*16
static __device__ __forceinline__ void gload16(const short* g, lds_short_t* l) {
  __builtin_amdgcn_global_load_lds(
      (const __attribute__((address_space(1))) unsigned int*)g,
      (__attribute__((address_space(3))) unsigned int*)l, 16, 0, 0);
}

__global__ __launch_bounds__(256) void cvt_f32_bf16(const float* __restrict__ src,
                                                    short* __restrict__ dst,
                                                    int n4) {
  int i = blockIdx.x * 256 + threadIdx.x;
  if (i >= n4) return;
  float4 v = ((const float4*)src)[i];
  short4v o;
  o.x = f2bf(v.x); o.y = f2bf(v.y); o.z = f2bf(v.z); o.w = f2bf(v.w);
  ((short4v*)dst)[i] = o;
}

// all 4 weight matrices in one launch: gridDim=(1024,4)
__global__ __launch_bounds__(256) void cvt_w4(const float* __restrict__ w0,
                                              const float* __restrict__ w1,
                                              const float* __restrict__ w2,
                                              const float* __restrict__ w3,
                                              short* __restrict__ dst) {
  const int y = blockIdx.y;
  const float* src = (y == 0) ? w0 : (y == 1) ? w1 : (y == 2) ? w2 : w3;
  int i = blockIdx.x * 256 + threadIdx.x;  // < 262144 exactly
  float4 v = ((const float4*)src)[i];
  short4v o;
  o.x = f2bf(v.x); o.y = f2bf(v.y); o.z = f2bf(v.z); o.w = f2bf(v.w);
  ((short4v*)(dst))[(size_t)y * 262144 + i] = o;
}

// ---------------------------------------------------------------------------
// QKV GEMM, 256x256 tile, counted-vmcnt schedule (r9: 3 barriers + 3 waits
// per K-tile; r8's 8 barriers + 4 waits starved DMA flight).
// Regions (16KB each, dbuf):
//   R0 = A rows {0-63,128-191}   (mh0; read P0)
//   R1 = B rows {wn*64+0..31}    (nh0; read P0, frags HELD to P3)
//   R2 = B rows {wn*64+32..63}   (nh1; read P1, held to P2)
//   R3 = A rows {64-127,192-255} (mh1; read P2)
// Stage order per tile: S0@P0, S1@P1, S2@P2a, S3@P2b (regions of kt+1).
// Guard chain (per-wave vmcnt + barrier broadcast):
//   end-P0  vmcnt(4) -> S(kt,2) landed  (guards P1 read of R2)
//   end-P1  vmcnt(4) -> S(kt,3) landed  (guards P2 read of R3)
//   end-tile vmcnt(4) -> S(kt+1,0),S(kt+1,1) landed (guards next P0)
// P2+P3 run barrier-free (P3 reads nothing: fa held from P2, fb0 from P0).
// Last tile (no new stages): vmcnt(2)/(0) peel via uniform branch.
// ---------------------------------------------------------------------------
__global__ __launch_bounds__(512, 2) void gemm_qkv_8p(
    const short* __restrict__ A, const short* __restrict__ W,
    short* __restrict__ Qb, short* __restrict__ Kb, short* __restrict__ Vt) {
  __shared__ short lds[2][4][8192];  // 128 KiB
  const int tid = threadIdx.x, lane = tid & 63, w = tid >> 6;
  const int wm = w >> 2, wn = w & 3;
  const int ll = lane & 15, lh = lane >> 4;
  // XCD-bijective swizzle (nwg=384=8*48)
  const int wg = ((int)blockIdx.x & 7) * 48 + ((int)blockIdx.x >> 3);
  const int m0 = (wg / 12) * 256, n0 = (wg % 12) * 256;

  lds_short_t* L3 = (lds_short_t*)&lds[0][0][0];

  // staging geometry: region = 16KB = 1024 slots of 16B; 2 issues/thread.
  const short* Asrc[2];
  const short* Bsrc[2];
  int dstOff[2];
#pragma unroll
  for (int i = 0; i < 2; ++i) {
    int slot = i * 512 + tid;
    int ridx = slot >> 3, g = slot & 7;
    int gp = g ^ (ridx & 7);  // pre-swizzled source granule
    Asrc[i] = A + (size_t)(m0 + (ridx & 63) + ((ridx >> 6) << 7)) * 1024 + gp * 8;
    Bsrc[i] = W + (size_t)(n0 + ((ridx >> 5) << 6) + (ridx & 31)) * 1024 + gp * 8;
    dstOff[i] = (i * 512 + w * 64) * 8;  // wave-uniform LDS base (shorts)
  }

  f32x4 acc[8][4] = {};
  bf16x8 fa[4][2];   // A frags (mh0 in P0/P1; mh1 in P2/P3)
  bf16x8 fb0[2][2];  // B-nh0 frags, HELD P0 -> P3
  bf16x8 fb1[2][2];  // B-nh1 frags, held P1 -> P2

  // prologue: stage tile 0 regions R0..R3 into buf 0 (issue order = age)
#pragma unroll
  for (int i = 0; i < 2; ++i) gload16(Asrc[i], L3 + 0 * 8192 + dstOff[i]);
#pragma unroll
  for (int i = 0; i < 2; ++i) gload16(Bsrc[i], L3 + 1 * 8192 + dstOff[i]);
#pragma unroll
  for (int i = 0; i < 2; ++i)
    gload16(Bsrc[i] + 32 * 1024, L3 + 2 * 8192 + dstOff[i]);
#pragma unroll
  for (int i = 0; i < 2; ++i)
    gload16(Asrc[i] + 64 * 1024, L3 + 3 * 8192 + dstOff[i]);
  asm volatile("s_waitcnt vmcnt(4)" ::: "memory");  // R0,R1 landed (per-wave)
  __builtin_amdgcn_s_barrier();                     // -> landed for all waves

  for (int kt = 0; kt < 16; ++kt) {
    const int c = kt & 1;
    const int nb = (c ^ 1) * 32768;
    const int kn = (kt + 1) * 64;
    const bool last = (kt == 15);

    // ---------------- P0: quadrant (mh0, nh0); reads R0, R1 ----------------
#pragma unroll
    for (int mi = 0; mi < 4; ++mi) {
      int ridx = wm * 64 + mi * 16 + ll;
#pragma unroll
      for (int kh = 0; kh < 2; ++kh)
        fa[mi][kh] = *(const bf16x8*)&lds[c][0][ridx * 64 +
                                               (((kh * 4 + lh) ^ (ll & 7)) * 8)];
    }
#pragma unroll
    for (int ni = 0; ni < 2; ++ni) {
      int ridx = wn * 32 + ni * 16 + ll;
#pragma unroll
      for (int kh = 0; kh < 2; ++kh)
        fb0[ni][kh] = *(const bf16x8*)&lds[c][1][ridx * 64 +
                                                 (((kh * 4 + lh) ^ (ll & 7)) * 8)];
    }
    if (!last) {  // stage S(kt+1,0) = A-mh0'
#pragma unroll
      for (int i = 0; i < 2; ++i)
        gload16(Asrc[i] + kn, L3 + nb + 0 * 8192 + dstOff[i]);
      asm volatile("s_waitcnt vmcnt(4)" ::: "memory");  // S(kt,2) landed
    } else {
      asm volatile("s_waitcnt vmcnt(2)" ::: "memory");
    }
    __builtin_amdgcn_s_barrier();
    __builtin_amdgcn_s_setprio(1);
#pragma unroll
    for (int mi = 0; mi < 4; ++mi)
#pragma unroll
      for (int ni = 0; ni < 2; ++ni)
#pragma unroll
        for (int kh = 0; kh < 2; ++kh)
          acc[mi][ni] = __builtin_amdgcn_mfma_f32_16x16x32_bf16(
              fa[mi][kh], fb0[ni][kh], acc[mi][ni], 0, 0, 0);
    __builtin_amdgcn_s_setprio(0);

    // ---------------- P1: quadrant (mh0, nh1); reads R2 ----------------
#pragma unroll
    for (int ni = 0; ni < 2; ++ni) {
      int ridx = wn * 32 + ni * 16 + ll;
#pragma unroll
      for (int kh = 0; kh < 2; ++kh)
        fb1[ni][kh] = *(const bf16x8*)&lds[c][2][ridx * 64 +
                                                 (((kh * 4 + lh) ^ (ll & 7)) * 8)];
    }
    if (!last) {  // stage S(kt+1,1) = B-nh0'
#pragma unroll
      for (int i = 0; i < 2; ++i)
        gload16(Bsrc[i] + kn, L3 + nb + 1 * 8192 + dstOff[i]);
      asm volatile("s_waitcnt vmcnt(4)" ::: "memory");  // S(kt,3) landed
    } else {
      asm volatile("s_waitcnt vmcnt(0)" ::: "memory");
    }
    __builtin_amdgcn_s_barrier();
    __builtin_amdgcn_s_setprio(1);
#pragma unroll
    for (int mi = 0; mi < 4; ++mi)
#pragma unroll
      for (int ni = 0; ni < 2; ++ni)
#pragma unroll
        for (int kh = 0; kh < 2; ++kh)
          acc[mi][2 + ni] = __builtin_amdgcn_mfma_f32_16x16x32_bf16(
              fa[mi][kh], fb1[ni][kh], acc[mi][2 + ni], 0, 0, 0);
    __builtin_amdgcn_s_setprio(0);

    // ------- P2+P3 (barrier-free): reads R3; (mh1,nh1) then (mh1,nh0) -------
#pragma unroll
    for (int mi = 0; mi < 4; ++mi) {
      int ridx = wm * 64 + mi * 16 + ll;
#pragma unroll
      for (int kh = 0; kh < 2; ++kh)
        fa[mi][kh] = *(const bf16x8*)&lds[c][3][ridx * 64 +
                                               (((kh * 4 + lh) ^ (ll & 7)) * 8)];
    }
    if (!last) {  // stage S(kt+1,2) = B-nh1'
#pragma unroll
      for (int i = 0; i < 2; ++i)
        gload16(Bsrc[i] + 32 * 1024 + kn, L3 + nb + 2 * 8192 + dstOff[i]);
    }
    __builtin_amdgcn_s_setprio(1);
#pragma unroll
    for (int mi = 0; mi < 4; ++mi)
#pragma unroll
      for (int ni = 0; ni < 2; ++ni)
#pragma unroll
        for (int kh = 0; kh < 2; ++kh)
          acc[4 + mi][2 + ni] = __builtin_amdgcn_mfma_f32_16x16x32_bf16(
              fa[mi][kh], fb1[ni][kh], acc[4 + mi][2 + ni], 0, 0, 0);
    __builtin_amdgcn_s_setprio(0);
    if (!last) {  // stage S(kt+1,3) = A-mh1'
#pragma unroll
      for (int i = 0; i < 2; ++i)
        gload16(Asrc[i] + 64 * 1024 + kn, L3 + nb + 3 * 8192 + dstOff[i]);
    }
    __builtin_amdgcn_s_setprio(1);
#pragma unroll
    for (int mi = 0; mi < 4; ++mi)
#pragma unroll
      for (int ni = 0; ni < 2; ++ni)
#pragma unroll
        for (int kh = 0; kh < 2; ++kh)
          acc[4 + mi][ni] = __builtin_amdgcn_mfma_f32_16x16x32_bf16(
              fa[mi][kh], fb0[ni][kh], acc[4 + mi][ni], 0, 0, 0);
    __builtin_amdgcn_s_setprio(0);
    if (!last) {
      asm volatile("s_waitcnt vmcnt(4)" ::: "memory");  // S(kt+1,0/1) landed
      __builtin_amdgcn_s_barrier();
    }
  }

  // epilogue: C layout col=ll, row=lh*4+r per frag; scatter to Qb/Kb/Vt
#pragma unroll
  for (int mi = 0; mi < 8; ++mi) {
#pragma unroll
    for (int ni = 0; ni < 4; ++ni) {
#pragma unroll
      for (int r = 0; r < 4; ++r) {
        int row = m0 + wm * 128 + mi * 16 + lh * 4 + r;
        int n = n0 + wn * 64 + ni * 16 + ll;
        float v = acc[mi][ni][r];
        if (n < 1024) {
          Qb[(size_t)row * 1024 + n] = f2bf(v * 0.18033688f);  // scale*log2e
        } else if (n < 2048) {
          Kb[(size_t)row * 1024 + (n - 1024)] = f2bf(v);
        } else {
          int cc = n - 2048, hh = cc >> 6, dd = cc & 63;
          int bb = row >> 11, ss = row & 2047;
          Vt[(size_t)((bb * 16 + hh) * 64 + dd) * 2048 + ss] = f2bf(v);
        }
      }
    }
  }
}

// Out-projection GEMM (proven 128x128 2-phase). A bf16 [M,1024], W bf16
// [N,1024], f32 out + bias.
__global__ __launch_bounds__(256) void gemm_out(
    const short* __restrict__ A, const short* __restrict__ W,
    const float* __restrict__ bias, float* __restrict__ outF) {
  __shared__ short As[128 * 32];
  __shared__ short Bs[128 * 32];
  const int tid = threadIdx.x;
  const int m0 = blockIdx.x * 128, n0 = blockIdx.y * 128;
  const int lane = tid & 63, w = tid >> 6;
  const int wr = w >> 1, wc = w & 1;
  const int ll = lane & 15, lh = lane >> 4;

  lds_short_t* As3 = (lds_short_t*)As;
  lds_short_t* Bs3 = (lds_short_t*)Bs;

  const short* Abase[2];
  const short* Wbase[2];
#pragma unroll
  for (int i = 0; i < 2; ++i) {
    int slot = i * 256 + w * 64 + lane;
    int row = slot >> 2;
    int col = ((slot & 3) ^ (row & 3)) * 8;
    Abase[i] = A + (size_t)(m0 + row) * 1024 + col;
    Wbase[i] = W + (size_t)(n0 + row) * 1024 + col;
  }

  f32x4 acc[4][4] = {};

  for (int k0 = 0; k0 < 1024; k0 += 32) {
    __syncthreads();
#pragma unroll
    for (int i = 0; i < 2; ++i) {
      gload16(Abase[i] + k0, As3 + (i * 256 + w * 64) * 8);
      gload16(Wbase[i] + k0, Bs3 + (i * 256 + w * 64) * 8);
    }
    __syncthreads();

    bf16x8 fa[4], fb[4];
#pragma unroll
    for (int mi = 0; mi < 4; ++mi) {
      int r = wr * 64 + mi * 16 + ll;
      fa[mi] = *(const bf16x8*)&As[r * 32 + ((lh ^ (ll & 3)) * 8)];
    }
#pragma unroll
    for (int ni = 0; ni < 4; ++ni) {
      int r = wc * 64 + ni * 16 + ll;
      fb[ni] = *(const bf16x8*)&Bs[r * 32 + ((lh ^ (ll & 3)) * 8)];
    }
#pragma unroll
    for (int mi = 0; mi < 4; ++mi)
#pragma unroll
      for (int ni = 0; ni < 4; ++ni)
        acc[mi][ni] = __builtin_amdgcn_mfma_f32_16x16x32_bf16(
            fa[mi], fb[ni], acc[mi][ni], 0, 0, 0);
  }

#pragma unroll
  for (int mi = 0; mi < 4; ++mi)
#pragma unroll
    for (int ni = 0; ni < 4; ++ni)
#pragma unroll
      for (int r = 0; r < 4; ++r) {
        int row = m0 + wr * 64 + mi * 16 + lh * 4 + r;
        int n = n0 + wc * 64 + ni * 16 + ll;
        outF[(size_t)row * 1024 + n] = acc[mi][ni][r] + bias[n];
      }
}

// Causal flash attention, fixed-max softmax, 32x32 MFMA, swapped QK^T
// (v7: proven @ round 7).
__global__ __launch_bounds__(256, 3) void attn_v7(const short* __restrict__ Q,
                                                  const short* __restrict__ K,
                                                  const short* __restrict__ Vt,
                                                  short* __restrict__ AO) {
  __shared__ short Ks[2][64 * 64];
  __shared__ short Vs[2][64 * 64];
  const int tid = threadIdx.x, lane = tid & 63, w = tid >> 6;
  const int l31 = lane & 31, lh2 = lane >> 5;
  const int id = blockIdx.x;
  const int bh = id & 63;
  const int qs = id >> 6;
  const int jj = qs >> 2;
  const int qb = (jj == 0) ? qs : (jj == 1) ? 19 - qs : (jj == 2) ? qs - 4 : 23 - qs;
  const int b = bh >> 4, h = bh & 15;
  const int q0 = qb * 128;
  const int R = q0 + w * 32;             // wave's first q-row
  const int kw_last = (R + 31) >> 6;     // wave's diagonal k-tile
  const int kb_max = (q0 + 127) >> 6;    // block's last k-tile
  const short* Qp = Q + (size_t)b * Sc * Dc + h * 64;
  const short* Kp = K + (size_t)b * Sc * Dc + h * 64;
  const short* Vp = Vt + (size_t)bh * 64 * Sc;

  lds_short_t* Ks3 = (lds_short_t*)Ks;
  lds_short_t* Vs3 = (lds_short_t*)Vs;

  bf16x8 qf[4];
#pragma unroll
  for (int dk = 0; dk < 4; ++dk)
    qf[dk] = *(const bf16x8*)&Qp[(size_t)(R + l31) * Dc + dk * 16 + lh2 * 8];

  const short* Kst[2];
  const short* Vst[2];
  int ldsOff[2];
#pragma unroll
  for (int i = 0; i < 2; ++i) {
    int slot = i * 256 + w * 64 + lane;
    int row = slot >> 3;
    int col = ((slot & 7) ^ (row & 7)) * 8;  // pre-swizzled source group
    Kst[i] = Kp + (size_t)row * 1024 + col;
    Vst[i] = Vp + (size_t)row * 2048 + col;
    ldsOff[i] = (i * 256 + w * 64) * 8;
  }

  f32x16 o0 = {}, o1 = {};
  float lrun = 0.f;

#pragma unroll
  for (int i = 0; i < 2; ++i) {
    gload16(Kst[i], Ks3 + ldsOff[i]);
    gload16(Vst[i], Vs3 + ldsOff[i]);
  }
  int cur = 0;

  for (int kb = 0; kb <= kb_max; ++kb) {
    __syncthreads();
    if (kb < kb_max) {
      int nb = cur ^ 1;
#pragma unroll
      for (int i = 0; i < 2; ++i) {
        gload16(Kst[i] + (size_t)(kb + 1) * 65536, Ks3 + nb * 4096 + ldsOff[i]);
        gload16(Vst[i] + (kb + 1) * 64, Vs3 + nb * 4096 + ldsOff[i]);
      }
    }

    if (kb <= kw_last) {
      const bool diag = (kb == kw_last);
      const bool skipHi = diag && ((R & 63) == 0);

      f32x16 sv0 = {}, sv1 = {};
      {
        const int row = l31, rx = row & 7;
#pragma unroll
        for (int dk = 0; dk < 4; ++dk) {
          bf16x8 kf =
              *(const bf16x8*)&Ks[cur][row * 64 + (((dk * 2 + lh2) ^ rx) * 8)];
          sv0 = __builtin_amdgcn_mfma_f32_32x32x16_bf16(kf, qf[dk], sv0, 0, 0, 0);
        }
      }
      if (!skipHi) {
        const int row = 32 + l31, rx = row & 7;
#pragma unroll
        for (int dk = 0; dk < 4; ++dk) {
          bf16x8 kf =
              *(const bf16x8*)&Ks[cur][row * 64 + (((dk * 2 + lh2) ^ rx) * 8)];
          sv1 = __builtin_amdgcn_mfma_f32_32x32x16_bf16(kf, qf[dk], sv1, 0, 0, 0);
        }
      }

      float ts = 0.f;
      if (!diag) {
#pragma unroll
        for (int r = 0; r < 16; ++r) {
          float e0 = exp2f(sv0[r]);
          float e1 = exp2f(sv1[r]);
          sv0[r] = e0; sv1[r] = e1;
          ts += e0 + e1;
        }
      } else if (skipHi) {
#pragma unroll
        for (int r = 0; r < 16; ++r) {
          int kl = (r & 3) + 8 * (r >> 2) + 4 * lh2;
          float e = (kl > l31) ? 0.f : exp2f(sv0[r]);
          sv0[r] = e;
          ts += e;
        }
      } else {
#pragma unroll
        for (int r = 0; r < 16; ++r) {
          float e = exp2f(sv0[r]);
          sv0[r] = e;
          ts += e;
        }
#pragma unroll
        for (int r = 0; r < 16; ++r) {
          int kl = (r & 3) + 8 * (r >> 2) + 4 * lh2;
          float e = (kl > l31) ? 0.f : exp2f(sv1[r]);
          sv1[r] = e;
          ts += e;
        }
      }
      lrun += ts;

      short4v pa[8];
#pragma unroll
      for (int t = 0; t < 4; ++t) {
        union { unsigned int u[2]; short4v s; } pk;
        pk.u[0] = cvtpk(sv0[4 * t + 0], sv0[4 * t + 1]);
        pk.u[1] = cvtpk(sv0[4 * t + 2], sv0[4 * t + 3]);
        pa[t] = pk.s;
      }
      if (skipHi) {
        const int r0 = l31, rx0 = r0 & 7;
        const int r1 = 32 + l31, rx1 = r1 & 7;
#pragma unroll
        for (int t = 0; t < 4; ++t) {
          short4v vb0 =
              *(const short4v*)&Vs[cur][r0 * 64 + ((t ^ rx0) * 8) + lh2 * 4];
          o0 = __builtin_amdgcn_mfma_f32_32x32x8bf16_1k(pa[t], vb0, o0, 0, 0, 0);
          short4v vb1 =
              *(const short4v*)&Vs[cur][r1 * 64 + ((t ^ rx1) * 8) + lh2 * 4];
          o1 = __builtin_amdgcn_mfma_f32_32x32x8bf16_1k(pa[t], vb1, o1, 0, 0, 0);
        }
      } else {
#pragma unroll
        for (int t = 0; t < 4; ++t) {
          union { unsigned int u[2]; short4v s; } pk;
          pk.u[0] = cvtpk(sv1[4 * t + 0], sv1[4 * t + 1]);
          pk.u[1] = cvtpk(sv1[4 * t + 2], sv1[4 * t + 3]);
          pa[4 + t] = pk.s;
        }
        const int r0 = l31, rx0 = r0 & 7;
        const int r1 = 32 + l31, rx1 = r1 & 7;
#pragma unroll
        for (int t = 0; t < 8; ++t) {
          short4v vb0 =
              *(const short4v*)&Vs[cur][r0 * 64 + ((t ^ rx0) * 8) + lh2 * 4];
          o0 = __builtin_amdgcn_mfma_f32_32x32x8bf16_1k(pa[t], vb0, o0, 0, 0, 0);
        }
#pragma unroll
        for (int t = 0; t < 8; ++t) {
          short4v vb1 =
              *(const short4v*)&Vs[cur][r1 * 64 + ((t ^ rx1) * 8) + lh2 * 4];
          o1 = __builtin_amdgcn_mfma_f32_32x32x8bf16_1k(pa[t], vb1, o1, 0, 0, 0);
        }
      }
    }
    cur ^= 1;
  }

  float ltot = lrun + __shfl_xor(lrun, 32);
#pragma unroll
  for (int r = 0; r < 16; ++r) {
    int qr = (r & 3) + 8 * (r >> 2) + 4 * lh2;
    float lq = __shfl(ltot, qr);
    float inv = 1.0f / lq;
    int rowg = R + qr;
    AO[((size_t)(b * Sc + rowg)) * Dc + h * 64 + l31] = f2bf(o0[r] * inv);
    AO[((size_t)(b * Sc + rowg)) * Dc + h * 64 + 32 + l31] = f2bf(o1[r] * inv);
  }
}

extern "C" void kernel_launch(void* const* d_in, const int* in_sizes, int n_in,
                              void* d_out, int out_size, void* d_ws,
                              size_t ws_size, hipStream_t stream) {
  const float* x = (const float*)d_in[0];
  const float* Wq = (const float*)d_in[1];
  const float* Wk = (const float*)d_in[2];
  const float* Wv = (const float*)d_in[3];
  const float* Wo = (const float*)d_in[4];
  const float* bo = (const float*)d_in[5];
  float* out = (float*)d_out;

  short* Qb = (short*)d_out;
  short* Kb = Qb + (size_t)8192 * 1024;
  short* xb = (short*)d_ws;
  short* AOb = xb;  // xb dead after QKV GEMM; attention writes AOb
  short* Wc = xb + (size_t)8192 * 1024;
  short* Vt = Wc + (size_t)4096 * 1024;

  dim3 blk(256);
  hipLaunchKernelGGL(cvt_f32_bf16, dim3(8192), blk, 0, stream, x, xb, 2097152);
  hipLaunchKernelGGL(cvt_w4, dim3(1024, 4), blk, 0, stream, Wq, Wk, Wv, Wo, Wc);

  hipLaunchKernelGGL(gemm_qkv_8p, dim3(384), dim3(512), 0, stream, xb, Wc, Qb,
                     Kb, Vt);

  hipLaunchKernelGGL(attn_v7, dim3(1024), blk, 0, stream, Qb, Kb, Vt, AOb);

  hipLaunchKernelGGL(gemm_out, dim3(64, 8), blk, 0, stream, AOb,
                     Wc + (size_t)3072 * 1024, bo, out);
}

// Round 10
// 188.075 us; speedup vs baseline: 1.0714x; 1.0578x over previous
//
#include <hip/hip_runtime.h>
#include <hip/hip_bf16.h>

// B=4, S=2048, D=1024, H=16, HD=64
constexpr int Sc = 2048, Dc = 1024;

typedef __attribute__((ext_vector_type(8))) short bf16x8;
typedef __attribute__((ext_vector_type(4))) short short4v;
typedef __attribute__((ext_vector_type(4))) float f32x4;
typedef __attribute__((ext_vector_type(16))) float f32x16;

static __device__ __forceinline__ short f2bf(float f) {
  __hip_bfloat16 h = __float2bfloat16(f);
  short s; __builtin_memcpy(&s, &h, 2);
  return s;
}

// packed f32x2 -> bf16x2 (RNE), single instruction on gfx950 (HW-verified r6)
static __device__ __forceinline__ unsigned int cvtpk(float lo, float hi) {
  unsigned int r;
  asm("v_cvt_pk_bf16_f32 %0, %1, %2" : "=v"(r) : "v"(lo), "v"(hi));
  return r;
}

typedef __attribute__((address_space(3))) short lds_short_t;

// async global->LDS, 16B per lane; LDS dest = wave-uniform base + lane*16
static __device__ __forceinline__ void gload16(const short* g, lds_short_t* l) {
  __builtin_amdgcn_global_load_lds(
      (const __attribute__((address_space(1))) unsigned int*)g,
      (__attribute__((address_space(3))) unsigned int*)l, 16, 0, 0);
}

__global__ __launch_bounds__(256) void cvt_f32_bf16(const float* __restrict__ src,
                                                    short* __restrict__ dst,
                                                    int n4) {
  int i = blockIdx.x * 256 + threadIdx.x;
  if (i >= n4) return;
  float4 v = ((const float4*)src)[i];
  short4v o;
  o.x = f2bf(v.x); o.y = f2bf(v.y); o.z = f2bf(v.z); o.w = f2bf(v.w);
  ((short4v*)dst)[i] = o;
}

// all 4 weight matrices in one launch: gridDim=(1024,4)
__global__ __launch_bounds__(256) void cvt_w4(const float* __restrict__ w0,
                                              const float* __restrict__ w1,
                                              const float* __restrict__ w2,
                                              const float* __restrict__ w3,
                                              short* __restrict__ dst) {
  const int y = blockIdx.y;
  const float* src = (y == 0) ? w0 : (y == 1) ? w1 : (y == 2) ? w2 : w3;
  int i = blockIdx.x * 256 + threadIdx.x;  // < 262144 exactly
  float4 v = ((const float4*)src)[i];
  short4v o;
  o.x = f2bf(v.x); o.y = f2bf(v.y); o.z = f2bf(v.z); o.w = f2bf(v.w);
  ((short4v*)(dst))[(size_t)y * 262144 + i] = o;
}

// ---------------------------------------------------------------------------
// 2-phase 128x128 GEMM, BK=64 (r10): 128B LDS rows -> 8-granule XOR swizzle
// (g ^ row&7) puts 16 lanes on 8 bank-slots x 2 lanes = 2-way = free (m136),
// vs BK=32's 4-way (measured 6.3e6 conflicts). 16 K-steps (half the barriers).
// LDS 32KB -> 3-4 blocks/CU TLP. C = A @ W^T; A bf16 [M,1024], W bf16 [N,1024].
// MODE 0: QKV fused epilogue -> Qb (prescaled), Kb, Vt.  MODE 1: f32 + bias.
// ---------------------------------------------------------------------------
template <int MODE>
__global__ __launch_bounds__(256) void gemm_bk64(
    const short* __restrict__ A, const short* __restrict__ W,
    const float* __restrict__ bias, short* __restrict__ Qb,
    short* __restrict__ Kb, short* __restrict__ Vt, float* __restrict__ outF) {
  __shared__ short As[128 * 64];
  __shared__ short Bs[128 * 64];
  const int tid = threadIdx.x;
  const int m0 = blockIdx.x * 128, n0 = blockIdx.y * 128;
  const int lane = tid & 63, w = tid >> 6;
  const int wr = w >> 1, wc = w & 1;
  const int ll = lane & 15, lh = lane >> 4;

  lds_short_t* As3 = (lds_short_t*)As;
  lds_short_t* Bs3 = (lds_short_t*)Bs;

  // staging: 1024 slots of 16B per tile; slot = i*256 + tid; row = slot>>3,
  // granule g = slot&7, source granule pre-swizzled gp = g ^ (row&7).
  const short* Abase[4];
  const short* Wbase[4];
  int dstOff[4];
#pragma unroll
  for (int i = 0; i < 4; ++i) {
    int slot = i * 256 + tid;
    int row = slot >> 3;
    int gp = (slot & 7) ^ (row & 7);
    Abase[i] = A + (size_t)(m0 + row) * 1024 + gp * 8;
    Wbase[i] = W + (size_t)(n0 + row) * 1024 + gp * 8;
    dstOff[i] = (i * 256 + w * 64) * 8;
  }

  f32x4 acc[4][4] = {};

  for (int k0 = 0; k0 < 1024; k0 += 64) {
    __syncthreads();
#pragma unroll
    for (int i = 0; i < 4; ++i) gload16(Abase[i] + k0, As3 + dstOff[i]);
#pragma unroll
    for (int i = 0; i < 4; ++i) gload16(Wbase[i] + k0, Bs3 + dstOff[i]);
    __syncthreads();  // drains vmcnt -> tiles staged for all waves

    bf16x8 fa[4][2], fb[4][2];
#pragma unroll
    for (int mi = 0; mi < 4; ++mi) {
      int r = wr * 64 + mi * 16 + ll;
#pragma unroll
      for (int kh = 0; kh < 2; ++kh)
        fa[mi][kh] =
            *(const bf16x8*)&As[r * 64 + (((kh * 4 + lh) ^ (ll & 7)) * 8)];
    }
#pragma unroll
    for (int ni = 0; ni < 4; ++ni) {
      int r = wc * 64 + ni * 16 + ll;
#pragma unroll
      for (int kh = 0; kh < 2; ++kh)
        fb[ni][kh] =
            *(const bf16x8*)&Bs[r * 64 + (((kh * 4 + lh) ^ (ll & 7)) * 8)];
    }
#pragma unroll
    for (int mi = 0; mi < 4; ++mi)
#pragma unroll
      for (int ni = 0; ni < 4; ++ni)
#pragma unroll
        for (int kh = 0; kh < 2; ++kh)
          acc[mi][ni] = __builtin_amdgcn_mfma_f32_16x16x32_bf16(
              fa[mi][kh], fb[ni][kh], acc[mi][ni], 0, 0, 0);
  }

#pragma unroll
  for (int mi = 0; mi < 4; ++mi) {
#pragma unroll
    for (int ni = 0; ni < 4; ++ni) {
#pragma unroll
      for (int r = 0; r < 4; ++r) {
        int row = m0 + wr * 64 + mi * 16 + lh * 4 + r;
        int n = n0 + wc * 64 + ni * 16 + ll;
        float v = acc[mi][ni][r];
        if constexpr (MODE == 1) {
          outF[(size_t)row * 1024 + n] = v + bias[n];
        } else {
          if (n < 1024) {
            Qb[(size_t)row * 1024 + n] = f2bf(v * 0.18033688f);  // scale*log2e
          } else if (n < 2048) {
            Kb[(size_t)row * 1024 + (n - 1024)] = f2bf(v);
          } else {
            int cc = n - 2048, hh = cc >> 6, dd = cc & 63;
            int bb = row >> 11, ss = row & 2047;
            Vt[(size_t)((bb * 16 + hh) * 64 + dd) * 2048 + ss] = f2bf(v);
          }
        }
      }
    }
  }
}

// Causal flash attention, fixed-max softmax, 32x32 MFMA, swapped QK^T
// (v7: proven @ round 7).
__global__ __launch_bounds__(256, 3) void attn_v7(const short* __restrict__ Q,
                                                  const short* __restrict__ K,
                                                  const short* __restrict__ Vt,
                                                  short* __restrict__ AO) {
  __shared__ short Ks[2][64 * 64];
  __shared__ short Vs[2][64 * 64];
  const int tid = threadIdx.x, lane = tid & 63, w = tid >> 6;
  const int l31 = lane & 31, lh2 = lane >> 5;
  const int id = blockIdx.x;
  const int bh = id & 63;
  const int qs = id >> 6;
  const int jj = qs >> 2;
  const int qb = (jj == 0) ? qs : (jj == 1) ? 19 - qs : (jj == 2) ? qs - 4 : 23 - qs;
  const int b = bh >> 4, h = bh & 15;
  const int q0 = qb * 128;
  const int R = q0 + w * 32;             // wave's first q-row
  const int kw_last = (R + 31) >> 6;     // wave's diagonal k-tile
  const int kb_max = (q0 + 127) >> 6;    // block's last k-tile
  const short* Qp = Q + (size_t)b * Sc * Dc + h * 64;
  const short* Kp = K + (size_t)b * Sc * Dc + h * 64;
  const short* Vp = Vt + (size_t)bh * 64 * Sc;

  lds_short_t* Ks3 = (lds_short_t*)Ks;
  lds_short_t* Vs3 = (lds_short_t*)Vs;

  bf16x8 qf[4];
#pragma unroll
  for (int dk = 0; dk < 4; ++dk)
    qf[dk] = *(const bf16x8*)&Qp[(size_t)(R + l31) * Dc + dk * 16 + lh2 * 8];

  const short* Kst[2];
  const short* Vst[2];
  int ldsOff[2];
#pragma unroll
  for (int i = 0; i < 2; ++i) {
    int slot = i * 256 + w * 64 + lane;
    int row = slot >> 3;
    int col = ((slot & 7) ^ (row & 7)) * 8;  // pre-swizzled source group
    Kst[i] = Kp + (size_t)row * 1024 + col;
    Vst[i] = Vp + (size_t)row * 2048 + col;
    ldsOff[i] = (i * 256 + w * 64) * 8;
  }

  f32x16 o0 = {}, o1 = {};
  float lrun = 0.f;

#pragma unroll
  for (int i = 0; i < 2; ++i) {
    gload16(Kst[i], Ks3 + ldsOff[i]);
    gload16(Vst[i], Vs3 + ldsOff[i]);
  }
  int cur = 0;

  for (int kb = 0; kb <= kb_max; ++kb) {
    __syncthreads();
    if (kb < kb_max) {
      int nb = cur ^ 1;
#pragma unroll
      for (int i = 0; i < 2; ++i) {
        gload16(Kst[i] + (size_t)(kb + 1) * 65536, Ks3 + nb * 4096 + ldsOff[i]);
        gload16(Vst[i] + (kb + 1) * 64, Vs3 + nb * 4096 + ldsOff[i]);
      }
    }

    if (kb <= kw_last) {
      const bool diag = (kb == kw_last);
      const bool skipHi = diag && ((R & 63) == 0);

      f32x16 sv0 = {}, sv1 = {};
      {
        const int row = l31, rx = row & 7;
#pragma unroll
        for (int dk = 0; dk < 4; ++dk) {
          bf16x8 kf =
              *(const bf16x8*)&Ks[cur][row * 64 + (((dk * 2 + lh2) ^ rx) * 8)];
          sv0 = __builtin_amdgcn_mfma_f32_32x32x16_bf16(kf, qf[dk], sv0, 0, 0, 0);
        }
      }
      if (!skipHi) {
        const int row = 32 + l31, rx = row & 7;
#pragma unroll
        for (int dk = 0; dk < 4; ++dk) {
          bf16x8 kf =
              *(const bf16x8*)&Ks[cur][row * 64 + (((dk * 2 + lh2) ^ rx) * 8)];
          sv1 = __builtin_amdgcn_mfma_f32_32x32x16_bf16(kf, qf[dk], sv1, 0, 0, 0);
        }
      }

      float ts = 0.f;
      if (!diag) {
#pragma unroll
        for (int r = 0; r < 16; ++r) {
          float e0 = exp2f(sv0[r]);
          float e1 = exp2f(sv1[r]);
          sv0[r] = e0; sv1[r] = e1;
          ts += e0 + e1;
        }
      } else if (skipHi) {
#pragma unroll
        for (int r = 0; r < 16; ++r) {
          int kl = (r & 3) + 8 * (r >> 2) + 4 * lh2;
          float e = (kl > l31) ? 0.f : exp2f(sv0[r]);
          sv0[r] = e;
          ts += e;
        }
      } else {
#pragma unroll
        for (int r = 0; r < 16; ++r) {
          float e = exp2f(sv0[r]);
          sv0[r] = e;
          ts += e;
        }
#pragma unroll
        for (int r = 0; r < 16; ++r) {
          int kl = (r & 3) + 8 * (r >> 2) + 4 * lh2;
          float e = (kl > l31) ? 0.f : exp2f(sv1[r]);
          sv1[r] = e;
          ts += e;
        }
      }
      lrun += ts;

      short4v pa[8];
#pragma unroll
      for (int t = 0; t < 4; ++t) {
        union { unsigned int u[2]; short4v s; } pk;
        pk.u[0] = cvtpk(sv0[4 * t + 0], sv0[4 * t + 1]);
        pk.u[1] = cvtpk(sv0[4 * t + 2], sv0[4 * t + 3]);
        pa[t] = pk.s;
      }
      if (skipHi) {
        const int r0 = l31, rx0 = r0 & 7;
        const int r1 = 32 + l31, rx1 = r1 & 7;
#pragma unroll
        for (int t = 0; t < 4; ++t) {
          short4v vb0 =
              *(const short4v*)&Vs[cur][r0 * 64 + ((t ^ rx0) * 8) + lh2 * 4];
          o0 = __builtin_amdgcn_mfma_f32_32x32x8bf16_1k(pa[t], vb0, o0, 0, 0, 0);
          short4v vb1 =
              *(const short4v*)&Vs[cur][r1 * 64 + ((t ^ rx1) * 8) + lh2 * 4];
          o1 = __builtin_amdgcn_mfma_f32_32x32x8bf16_1k(pa[t], vb1, o1, 0, 0, 0);
        }
      } else {
#pragma unroll
        for (int t = 0; t < 4; ++t) {
          union { unsigned int u[2]; short4v s; } pk;
          pk.u[0] = cvtpk(sv1[4 * t + 0], sv1[4 * t + 1]);
          pk.u[1] = cvtpk(sv1[4 * t + 2], sv1[4 * t + 3]);
          pa[4 + t] = pk.s;
        }
        const int r0 = l31, rx0 = r0 & 7;
        const int r1 = 32 + l31, rx1 = r1 & 7;
#pragma unroll
        for (int t = 0; t < 8; ++t) {
          short4v vb0 =
              *(const short4v*)&Vs[cur][r0 * 64 + ((t ^ rx0) * 8) + lh2 * 4];
          o0 = __builtin_amdgcn_mfma_f32_32x32x8bf16_1k(pa[t], vb0, o0, 0, 0, 0);
        }
#pragma unroll
        for (int t = 0; t < 8; ++t) {
          short4v vb1 =
              *(const short4v*)&Vs[cur][r1 * 64 + ((t ^ rx1) * 8) + lh2 * 4];
          o1 = __builtin_amdgcn_mfma_f32_32x32x8bf16_1k(pa[t], vb1, o1, 0, 0, 0);
        }
      }
    }
    cur ^= 1;
  }

  float ltot = lrun + __shfl_xor(lrun, 32);
#pragma unroll
  for (int r = 0; r < 16; ++r) {
    int qr = (r & 3) + 8 * (r >> 2) + 4 * lh2;
    float lq = __shfl(ltot, qr);
    float inv = 1.0f / lq;
    int rowg = R + qr;
    AO[((size_t)(b * Sc + rowg)) * Dc + h * 64 + l31] = f2bf(o0[r] * inv);
    AO[((size_t)(b * Sc + rowg)) * Dc + h * 64 + 32 + l31] = f2bf(o1[r] * inv);
  }
}

extern "C" void kernel_launch(void* const* d_in, const int* in_sizes, int n_in,
                              void* d_out, int out_size, void* d_ws,
                              size_t ws_size, hipStream_t stream) {
  const float* x = (const float*)d_in[0];
  const float* Wq = (const float*)d_in[1];
  const float* Wk = (const float*)d_in[2];
  const float* Wv = (const float*)d_in[3];
  const float* Wo = (const float*)d_in[4];
  const float* bo = (const float*)d_in[5];
  float* out = (float*)d_out;

  short* Qb = (short*)d_out;
  short* Kb = Qb + (size_t)8192 * 1024;
  short* xb = (short*)d_ws;
  short* AOb = xb;  // xb dead after QKV GEMM; attention writes AOb
  short* Wc = xb + (size_t)8192 * 1024;
  short* Vt = Wc + (size_t)4096 * 1024;

  dim3 blk(256);
  hipLaunchKernelGGL(cvt_f32_bf16, dim3(8192), blk, 0, stream, x, xb, 2097152);
  hipLaunchKernelGGL(cvt_w4, dim3(1024, 4), blk, 0, stream, Wq, Wk, Wv, Wo, Wc);

  hipLaunchKernelGGL((gemm_bk64<0>), dim3(64, 24), blk, 0, stream, xb, Wc,
                     (const float*)nullptr, Qb, Kb, Vt, (float*)nullptr);

  hipLaunchKernelGGL(attn_v7, dim3(1024), blk, 0, stream, Qb, Kb, Vt, AOb);

  hipLaunchKernelGGL((gemm_bk64<1>), dim3(64, 8), blk, 0, stream, AOb,
                     Wc + (size_t)3072 * 1024, bo, (short*)nullptr,
                     (short*)nullptr, (short*)nullptr, out);
}

// Round 11
// 181.054 us; speedup vs baseline: 1.1130x; 1.0388x over previous
//
#include <hip/hip_runtime.h>
#include <hip/hip_bf16.h>

// B=4, S=2048, D=1024, H=16, HD=64
constexpr int Sc = 2048, Dc = 1024;

typedef __attribute__((ext_vector_type(8))) short bf16x8;
typedef __attribute__((ext_vector_type(4))) short short4v;
typedef __attribute__((ext_vector_type(4))) float f32x4;
typedef __attribute__((ext_vector_type(16))) float f32x16;

static __device__ __forceinline__ short f2bf(float f) {
  __hip_bfloat16 h = __float2bfloat16(f);
  short s; __builtin_memcpy(&s, &h, 2);
  return s;
}

// packed f32x2 -> bf16x2 (RNE), single instruction on gfx950 (HW-verified r6)
static __device__ __forceinline__ unsigned int cvtpk(float lo, float hi) {
  unsigned int r;
  asm("v_cvt_pk_bf16_f32 %0, %1, %2" : "=v"(r) : "v"(lo), "v"(hi));
  return r;
}

typedef __attribute__((address_space(3))) short lds_short_t;

// async global->LDS, 16B per lane; LDS dest = wave-uniform base + lane*16
static __device__ __forceinline__ void gload16(const short* g, lds_short_t* l) {
  __builtin_amdgcn_global_load_lds(
      (const __attribute__((address_space(1))) unsigned int*)g,
      (__attribute__((address_space(3))) unsigned int*)l, 16, 0, 0);
}

__global__ __launch_bounds__(256) void cvt_f32_bf16(const float* __restrict__ src,
                                                    short* __restrict__ dst,
                                                    int n4) {
  int i = blockIdx.x * 256 + threadIdx.x;
  if (i >= n4) return;
  float4 v = ((const float4*)src)[i];
  short4v o;
  o.x = f2bf(v.x); o.y = f2bf(v.y); o.z = f2bf(v.z); o.w = f2bf(v.w);
  ((short4v*)dst)[i] = o;
}

// all 4 weight matrices in one launch: gridDim=(1024,4)
__global__ __launch_bounds__(256) void cvt_w4(const float* __restrict__ w0,
                                              const float* __restrict__ w1,
                                              const float* __restrict__ w2,
                                              const float* __restrict__ w3,
                                              short* __restrict__ dst) {
  const int y = blockIdx.y;
  const float* src = (y == 0) ? w0 : (y == 1) ? w1 : (y == 2) ? w2 : w3;
  int i = blockIdx.x * 256 + threadIdx.x;  // < 262144 exactly
  float4 v = ((const float4*)src)[i];
  short4v o;
  o.x = f2bf(v.x); o.y = f2bf(v.y); o.z = f2bf(v.z); o.w = f2bf(v.w);
  ((short4v*)(dst))[(size_t)y * 262144 + i] = o;
}

// ---------------------------------------------------------------------------
// r11: 128x128 GEMM, BK=64, DOUBLE-BUFFERED with one barrier per K-step
// (attn_v7's proven staging structure). The r10 2-phase issued loads
// immediately before the barrier -> full HBM latency in every vmcnt(0) drain;
// here prefetch into buf^1 is issued right AFTER the barrier and drains a
// full K-step (~800 cyc) later: latency off the critical path, half the
// barriers. LDS 64KB -> 2 blocks/CU (8 waves: MFMA ~1240 vs LDS ~1000
// cyc/CU/K-step, balanced). Swizzle: 8-granule XOR (measured 0 conflicts).
// MODE 0: QKV fused epilogue -> Qb (prescaled), Kb, Vt.  MODE 1: f32 + bias.
// ---------------------------------------------------------------------------
template <int MODE>
__global__ __launch_bounds__(256) void gemm_db(
    const short* __restrict__ A, const short* __restrict__ W,
    const float* __restrict__ bias, short* __restrict__ Qb,
    short* __restrict__ Kb, short* __restrict__ Vt, float* __restrict__ outF) {
  __shared__ short As[2][128 * 64];
  __shared__ short Bs[2][128 * 64];
  const int tid = threadIdx.x;
  const int m0 = blockIdx.x * 128, n0 = blockIdx.y * 128;
  const int lane = tid & 63, w = tid >> 6;
  const int wr = w >> 1, wc = w & 1;
  const int ll = lane & 15, lh = lane >> 4;

  lds_short_t* As3 = (lds_short_t*)&As[0][0];
  lds_short_t* Bs3 = (lds_short_t*)&Bs[0][0];

  // staging: 1024 slots of 16B per tile; slot = i*256 + tid; row = slot>>3,
  // granule g = slot&7, source granule pre-swizzled gp = g ^ (row&7).
  const short* Abase[4];
  const short* Wbase[4];
  int dstOff[4];
#pragma unroll
  for (int i = 0; i < 4; ++i) {
    int slot = i * 256 + tid;
    int row = slot >> 3;
    int gp = (slot & 7) ^ (row & 7);
    Abase[i] = A + (size_t)(m0 + row) * 1024 + gp * 8;
    Wbase[i] = W + (size_t)(n0 + row) * 1024 + gp * 8;
    dstOff[i] = (i * 256 + w * 64) * 8;
  }

  f32x4 acc[4][4] = {};

  // prologue: stage K-tile 0 into buf 0
#pragma unroll
  for (int i = 0; i < 4; ++i) gload16(Abase[i], As3 + dstOff[i]);
#pragma unroll
  for (int i = 0; i < 4; ++i) gload16(Wbase[i], Bs3 + dstOff[i]);
  int cur = 0;

  for (int k0 = 0; k0 < 1024; k0 += 64) {
    // single barrier: drains vmcnt (buf[cur] staged for every wave) and all
    // waves are done reading buf[cur^1] from last iteration (safe to refill).
    __syncthreads();
    if (k0 < 960) {
      int nb = (cur ^ 1) * 8192;
#pragma unroll
      for (int i = 0; i < 4; ++i) gload16(Abase[i] + k0 + 64, As3 + nb + dstOff[i]);
#pragma unroll
      for (int i = 0; i < 4; ++i) gload16(Wbase[i] + k0 + 64, Bs3 + nb + dstOff[i]);
    }

    bf16x8 fa[4][2], fb[4][2];
#pragma unroll
    for (int mi = 0; mi < 4; ++mi) {
      int r = wr * 64 + mi * 16 + ll;
#pragma unroll
      for (int kh = 0; kh < 2; ++kh)
        fa[mi][kh] =
            *(const bf16x8*)&As[cur][r * 64 + (((kh * 4 + lh) ^ (ll & 7)) * 8)];
    }
#pragma unroll
    for (int ni = 0; ni < 4; ++ni) {
      int r = wc * 64 + ni * 16 + ll;
#pragma unroll
      for (int kh = 0; kh < 2; ++kh)
        fb[ni][kh] =
            *(const bf16x8*)&Bs[cur][r * 64 + (((kh * 4 + lh) ^ (ll & 7)) * 8)];
    }
    __builtin_amdgcn_s_setprio(1);
#pragma unroll
    for (int mi = 0; mi < 4; ++mi)
#pragma unroll
      for (int ni = 0; ni < 4; ++ni)
#pragma unroll
        for (int kh = 0; kh < 2; ++kh)
          acc[mi][ni] = __builtin_amdgcn_mfma_f32_16x16x32_bf16(
              fa[mi][kh], fb[ni][kh], acc[mi][ni], 0, 0, 0);
    __builtin_amdgcn_s_setprio(0);
    cur ^= 1;
  }

#pragma unroll
  for (int mi = 0; mi < 4; ++mi) {
#pragma unroll
    for (int ni = 0; ni < 4; ++ni) {
#pragma unroll
      for (int r = 0; r < 4; ++r) {
        int row = m0 + wr * 64 + mi * 16 + lh * 4 + r;
        int n = n0 + wc * 64 + ni * 16 + ll;
        float v = acc[mi][ni][r];
        if constexpr (MODE == 1) {
          outF[(size_t)row * 1024 + n] = v + bias[n];
        } else {
          if (n < 1024) {
            Qb[(size_t)row * 1024 + n] = f2bf(v * 0.18033688f);  // scale*log2e
          } else if (n < 2048) {
            Kb[(size_t)row * 1024 + (n - 1024)] = f2bf(v);
          } else {
            int cc = n - 2048, hh = cc >> 6, dd = cc & 63;
            int bb = row >> 11, ss = row & 2047;
            Vt[(size_t)((bb * 16 + hh) * 64 + dd) * 2048 + ss] = f2bf(v);
          }
        }
      }
    }
  }
}

// Causal flash attention, fixed-max softmax, 32x32 MFMA, swapped QK^T
// (v7: proven @ round 7).
__global__ __launch_bounds__(256, 3) void attn_v7(const short* __restrict__ Q,
                                                  const short* __restrict__ K,
                                                  const short* __restrict__ Vt,
                                                  short* __restrict__ AO) {
  __shared__ short Ks[2][64 * 64];
  __shared__ short Vs[2][64 * 64];
  const int tid = threadIdx.x, lane = tid & 63, w = tid >> 6;
  const int l31 = lane & 31, lh2 = lane >> 5;
  const int id = blockIdx.x;
  const int bh = id & 63;
  const int qs = id >> 6;
  const int jj = qs >> 2;
  const int qb = (jj == 0) ? qs : (jj == 1) ? 19 - qs : (jj == 2) ? qs - 4 : 23 - qs;
  const int b = bh >> 4, h = bh & 15;
  const int q0 = qb * 128;
  const int R = q0 + w * 32;             // wave's first q-row
  const int kw_last = (R + 31) >> 6;     // wave's diagonal k-tile
  const int kb_max = (q0 + 127) >> 6;    // block's last k-tile
  const short* Qp = Q + (size_t)b * Sc * Dc + h * 64;
  const short* Kp = K + (size_t)b * Sc * Dc + h * 64;
  const short* Vp = Vt + (size_t)bh * 64 * Sc;

  lds_short_t* Ks3 = (lds_short_t*)Ks;
  lds_short_t* Vs3 = (lds_short_t*)Vs;

  bf16x8 qf[4];
#pragma unroll
  for (int dk = 0; dk < 4; ++dk)
    qf[dk] = *(const bf16x8*)&Qp[(size_t)(R + l31) * Dc + dk * 16 + lh2 * 8];

  const short* Kst[2];
  const short* Vst[2];
  int ldsOff[2];
#pragma unroll
  for (int i = 0; i < 2; ++i) {
    int slot = i * 256 + w * 64 + lane;
    int row = slot >> 3;
    int col = ((slot & 7) ^ (row & 7)) * 8;  // pre-swizzled source group
    Kst[i] = Kp + (size_t)row * 1024 + col;
    Vst[i] = Vp + (size_t)row * 2048 + col;
    ldsOff[i] = (i * 256 + w * 64) * 8;
  }

  f32x16 o0 = {}, o1 = {};
  float lrun = 0.f;

#pragma unroll
  for (int i = 0; i < 2; ++i) {
    gload16(Kst[i], Ks3 + ldsOff[i]);
    gload16(Vst[i], Vs3 + ldsOff[i]);
  }
  int cur = 0;

  for (int kb = 0; kb <= kb_max; ++kb) {
    __syncthreads();
    if (kb < kb_max) {
      int nb = cur ^ 1;
#pragma unroll
      for (int i = 0; i < 2; ++i) {
        gload16(Kst[i] + (size_t)(kb + 1) * 65536, Ks3 + nb * 4096 + ldsOff[i]);
        gload16(Vst[i] + (kb + 1) * 64, Vs3 + nb * 4096 + ldsOff[i]);
      }
    }

    if (kb <= kw_last) {
      const bool diag = (kb == kw_last);
      const bool skipHi = diag && ((R & 63) == 0);

      f32x16 sv0 = {}, sv1 = {};
      {
        const int row = l31, rx = row & 7;
#pragma unroll
        for (int dk = 0; dk < 4; ++dk) {
          bf16x8 kf =
              *(const bf16x8*)&Ks[cur][row * 64 + (((dk * 2 + lh2) ^ rx) * 8)];
          sv0 = __builtin_amdgcn_mfma_f32_32x32x16_bf16(kf, qf[dk], sv0, 0, 0, 0);
        }
      }
      if (!skipHi) {
        const int row = 32 + l31, rx = row & 7;
#pragma unroll
        for (int dk = 0; dk < 4; ++dk) {
          bf16x8 kf =
              *(const bf16x8*)&Ks[cur][row * 64 + (((dk * 2 + lh2) ^ rx) * 8)];
          sv1 = __builtin_amdgcn_mfma_f32_32x32x16_bf16(kf, qf[dk], sv1, 0, 0, 0);
        }
      }

      float ts = 0.f;
      if (!diag) {
#pragma unroll
        for (int r = 0; r < 16; ++r) {
          float e0 = exp2f(sv0[r]);
          float e1 = exp2f(sv1[r]);
          sv0[r] = e0; sv1[r] = e1;
          ts += e0 + e1;
        }
      } else if (skipHi) {
#pragma unroll
        for (int r = 0; r < 16; ++r) {
          int kl = (r & 3) + 8 * (r >> 2) + 4 * lh2;
          float e = (kl > l31) ? 0.f : exp2f(sv0[r]);
          sv0[r] = e;
          ts += e;
        }
      } else {
#pragma unroll
        for (int r = 0; r < 16; ++r) {
          float e = exp2f(sv0[r]);
          sv0[r] = e;
          ts += e;
        }
#pragma unroll
        for (int r = 0; r < 16; ++r) {
          int kl = (r & 3) + 8 * (r >> 2) + 4 * lh2;
          float e = (kl > l31) ? 0.f : exp2f(sv1[r]);
          sv1[r] = e;
          ts += e;
        }
      }
      lrun += ts;

      short4v pa[8];
#pragma unroll
      for (int t = 0; t < 4; ++t) {
        union { unsigned int u[2]; short4v s; } pk;
        pk.u[0] = cvtpk(sv0[4 * t + 0], sv0[4 * t + 1]);
        pk.u[1] = cvtpk(sv0[4 * t + 2], sv0[4 * t + 3]);
        pa[t] = pk.s;
      }
      if (skipHi) {
        const int r0 = l31, rx0 = r0 & 7;
        const int r1 = 32 + l31, rx1 = r1 & 7;
#pragma unroll
        for (int t = 0; t < 4; ++t) {
          short4v vb0 =
              *(const short4v*)&Vs[cur][r0 * 64 + ((t ^ rx0) * 8) + lh2 * 4];
          o0 = __builtin_amdgcn_mfma_f32_32x32x8bf16_1k(pa[t], vb0, o0, 0, 0, 0);
          short4v vb1 =
              *(const short4v*)&Vs[cur][r1 * 64 + ((t ^ rx1) * 8) + lh2 * 4];
          o1 = __builtin_amdgcn_mfma_f32_32x32x8bf16_1k(pa[t], vb1, o1, 0, 0, 0);
        }
      } else {
#pragma unroll
        for (int t = 0; t < 4; ++t) {
          union { unsigned int u[2]; short4v s; } pk;
          pk.u[0] = cvtpk(sv1[4 * t + 0], sv1[4 * t + 1]);
          pk.u[1] = cvtpk(sv1[4 * t + 2], sv1[4 * t + 3]);
          pa[4 + t] = pk.s;
        }
        const int r0 = l31, rx0 = r0 & 7;
        const int r1 = 32 + l31, rx1 = r1 & 7;
#pragma unroll
        for (int t = 0; t < 8; ++t) {
          short4v vb0 =
              *(const short4v*)&Vs[cur][r0 * 64 + ((t ^ rx0) * 8) + lh2 * 4];
          o0 = __builtin_amdgcn_mfma_f32_32x32x8bf16_1k(pa[t], vb0, o0, 0, 0, 0);
        }
#pragma unroll
        for (int t = 0; t < 8; ++t) {
          short4v vb1 =
              *(const short4v*)&Vs[cur][r1 * 64 + ((t ^ rx1) * 8) + lh2 * 4];
          o1 = __builtin_amdgcn_mfma_f32_32x32x8bf16_1k(pa[t], vb1, o1, 0, 0, 0);
        }
      }
    }
    cur ^= 1;
  }

  float ltot = lrun + __shfl_xor(lrun, 32);
#pragma unroll
  for (int r = 0; r < 16; ++r) {
    int qr = (r & 3) + 8 * (r >> 2) + 4 * lh2;
    float lq = __shfl(ltot, qr);
    float inv = 1.0f / lq;
    int rowg = R + qr;
    AO[((size_t)(b * Sc + rowg)) * Dc + h * 64 + l31] = f2bf(o0[r] * inv);
    AO[((size_t)(b * Sc + rowg)) * Dc + h * 64 + 32 + l31] = f2bf(o1[r] * inv);
  }
}

extern "C" void kernel_launch(void* const* d_in, const int* in_sizes, int n_in,
                              void* d_out, int out_size, void* d_ws,
                              size_t ws_size, hipStream_t stream) {
  const float* x = (const float*)d_in[0];
  const float* Wq = (const float*)d_in[1];
  const float* Wk = (const float*)d_in[2];
  const float* Wv = (const float*)d_in[3];
  const float* Wo = (const float*)d_in[4];
  const float* bo = (const float*)d_in[5];
  float* out = (float*)d_out;

  short* Qb = (short*)d_out;
  short* Kb = Qb + (size_t)8192 * 1024;
  short* xb = (short*)d_ws;
  short* AOb = xb;  // xb dead after QKV GEMM; attention writes AOb
  short* Wc = xb + (size_t)8192 * 1024;
  short* Vt = Wc + (size_t)4096 * 1024;

  dim3 blk(256);
  hipLaunchKernelGGL(cvt_f32_bf16, dim3(8192), blk, 0, stream, x, xb, 2097152);
  hipLaunchKernelGGL(cvt_w4, dim3(1024, 4), blk, 0, stream, Wq, Wk, Wv, Wo, Wc);

  hipLaunchKernelGGL((gemm_db<0>), dim3(64, 24), blk, 0, stream, xb, Wc,
                     (const float*)nullptr, Qb, Kb, Vt, (float*)nullptr);

  hipLaunchKernelGGL(attn_v7, dim3(1024), blk, 0, stream, Qb, Kb, Vt, AOb);

  hipLaunchKernelGGL((gemm_db<1>), dim3(64, 8), blk, 0, stream, AOb,
                     Wc + (size_t)3072 * 1024, bo, (short*)nullptr,
                     (short*)nullptr, (short*)nullptr, out);
}